// Round 9
// baseline (312.078 us; speedup 1.0000x reference)
//
#include <hip/hip_runtime.h>
#include <stdint.h>

#define NNODES 10000
#define NEDGES 100000
#define DNODE 56
#define JTOT 1600
#define EBLK 782    // hidden-GEMM blocks (128 edges each)
#define TBLK 400    // G-transpose blocks (last grid block = scanhist)

typedef __attribute__((ext_vector_type(8))) short short8;
typedef __attribute__((ext_vector_type(16))) float floatx16;

__device__ __forceinline__ unsigned short f2bf(float f) {
  unsigned u = __float_as_uint(f);
  u = u + 0x7fffu + ((u >> 16) & 1u);
  return (unsigned short)(u >> 16);
}
__device__ __forceinline__ float bf2f(unsigned short u) {
  return __uint_as_float(((unsigned)u) << 16);
}

__device__ __forceinline__ float mishf(float x) {
  float e = __expf(x);
  float z = 1.f + e; z = z * z;
  float t = (z - 1.f) / (z + 1.f);
  t = (x > 40.f) ? 1.f : t;
  return x * t;
}

// async 16B global -> LDS; lds base wave-uniform (HW adds lane*16)
__device__ __forceinline__ void async_ld16(void* lds, const void* gp) {
  __builtin_amdgcn_global_load_lds(
      (const __attribute__((address_space(1))) unsigned int*)gp,
      (__attribute__((address_space(3))) unsigned int*)lds, 16, 0, 0);
}

// ---- fused: [0,EBLK) hidden GEMM; [EBLK,EBLK+TBLK) G pre-pack; last block: hist+scan
__global__ __launch_bounds__(256, 3) void k_hidtr(const float* __restrict__ ea,
                                                  const float* __restrict__ fc1w,
                                                  const float* __restrict__ fc1b,
                                                  const float* __restrict__ fc2w,
                                                  const int* __restrict__ eidx,
                                                  int* __restrict__ offs,
                                                  int* __restrict__ cursor,
                                                  int* __restrict__ gdone,
                                                  unsigned short* __restrict__ hb,
                                                  unsigned short* __restrict__ G) {
  __shared__ int4 SM4[2576];   // 41,216 B union: {T,E,b1s} | {hist,ts}
  const int bid = blockIdx.x, tid = threadIdx.x;

  if (bid == EBLK + TBLK) {    // ---- histogram + scan of edge_src -> offs/cursor
    int* hist = (int*)SM4;            // 10,000 ints
    int* ts   = hist + 10000;         // 256 ints
    for (int i = tid; i < NNODES; i += 256) hist[i] = 0;
    if (tid == 0) gdone[0] = 0;
    __syncthreads();
    for (int i = tid; i < NEDGES; i += 256) atomicAdd(&hist[eidx[i]], 1);
    __syncthreads();
    int s = 0;
    #pragma unroll 8
    for (int i = 0; i < 40; i++) {
      int idx = tid * 40 + i;
      if (idx < NNODES) s += hist[idx];
    }
    ts[tid] = s;
    __syncthreads();
    for (int o = 1; o < 256; o <<= 1) {
      int v = (tid >= o) ? ts[tid - o] : 0;
      __syncthreads();
      ts[tid] += v;
      __syncthreads();
    }
    int run = (tid == 0) ? 0 : ts[tid - 1];
    for (int i = 0; i < 40; i++) {
      int idx = tid * 40 + i;
      if (idx < NNODES) { int c = hist[idx]; offs[idx] = run; cursor[idx] = run; run += c; }
    }
    if (tid == 255) offs[NNODES] = ts[255];
    return;
  }

  if (bid >= EBLK) {           // ---- G pre-pack for 32x32x16 A-fragments
    int idx = (bid - EBLK) * 256 + tid;
    if (idx < 64 * JTOT) {
      int jt = idx >> 11;             // 2048 shorts per tile
      int r  = idx & 2047;
      int s  = r >> 9;                // sub-K (0..3)
      int l  = (r >> 3) & 63;         // lane
      int i  = r & 7;
      int j  = jt * 32 + (l & 31);
      int k  = s * 16 + (l >> 5) * 8 + i;
      G[idx] = f2bf(fc2w[k * JTOT + j]);
    }
    return;
  }

  // ---- hidden GEMM: 128 edges/block, 4 waves x 32 edges, MFMA 16x16x32 bf16
  unsigned short* T  = (unsigned short*)SM4;          // 64 x 72 bf16 (9,216 B)
  unsigned short* E  = (unsigned short*)SM4 + 4608;   // 128 x 72 bf16 (18,432 B)
  float* b1s = (float*)((char*)SM4 + 27648);          // 256 B
  const int e0 = bid * 128;
  if (tid < 64) b1s[tid] = fc1b[tid];
  #pragma unroll
  for (int it = 0; it < 4; it++) {
    int q = tid + 256 * it;
    int k = q >> 4, j4 = (q & 15) * 4;
    float4 v = *(const float4*)(fc1w + (size_t)q * 4);
    T[(j4+0)*72 + k] = f2bf(v.x);
    T[(j4+1)*72 + k] = f2bf(v.y);
    T[(j4+2)*72 + k] = f2bf(v.z);
    T[(j4+3)*72 + k] = f2bf(v.w);
  }
  #pragma unroll
  for (int it = 0; it < 8; it++) {
    int q = tid + 256 * it;
    int e = q >> 4, k4 = (q & 15) * 4;
    int ge = e0 + e;
    float4 v = (ge < NEDGES) ? *(const float4*)(ea + (size_t)ge * 64 + k4)
                             : make_float4(0.f, 0.f, 0.f, 0.f);
    ushort4 p;
    p.x = f2bf(v.x); p.y = f2bf(v.y); p.z = f2bf(v.z); p.w = f2bf(v.w);
    *(ushort4*)(&E[e*72 + k4]) = p;
  }
  __syncthreads();

  const int wave = tid >> 6, lane = tid & 63, col = lane & 15, rg = lane >> 4;
  typedef __attribute__((ext_vector_type(4))) float floatx4;
  short8 bf[2][2];
  #pragma unroll
  for (int nt = 0; nt < 2; nt++) {
    int er = wave*32 + nt*16 + col;
    bf[nt][0] = *(const short8*)(&E[er*72 + rg*8]);
    bf[nt][1] = *(const short8*)(&E[er*72 + 32 + rg*8]);
  }
  floatx4 acc[4][2];
  #pragma unroll
  for (int jt = 0; jt < 4; jt++) {
    int j = jt*16 + col;
    short8 a0 = *(const short8*)(&T[j*72 + rg*8]);
    short8 a1 = *(const short8*)(&T[j*72 + 32 + rg*8]);
    float4 bb = *(const float4*)(&b1s[jt*16 + rg*4]);
    #pragma unroll
    for (int nt = 0; nt < 2; nt++) {
      floatx4 c = {bb.x, bb.y, bb.z, bb.w};
      c = __builtin_amdgcn_mfma_f32_16x16x32_bf16(a0, bf[nt][0], c, 0, 0, 0);
      c = __builtin_amdgcn_mfma_f32_16x16x32_bf16(a1, bf[nt][1], c, 0, 0, 0);
      acc[jt][nt] = c;
    }
  }
  #pragma unroll
  for (int jt = 0; jt < 4; jt++)
    #pragma unroll
    for (int nt = 0; nt < 2; nt++) {
      ushort4 p;
      p.x = f2bf(mishf(acc[jt][nt][0]));
      p.y = f2bf(mishf(acc[jt][nt][1]));
      p.z = f2bf(mishf(acc[jt][nt][2]));
      p.w = f2bf(mishf(acc[jt][nt][3]));
      *(ushort4*)(&E[(wave*32 + nt*16 + col)*72 + jt*16 + rg*4]) = p;
    }
  #pragma unroll
  for (int it = 0; it < 4; it++) {
    int g = it*64 + lane;
    int r = g >> 3, c = g & 7;
    int ge = e0 + wave*32 + r;
    if (ge < NEDGES) {
      short8 v = *(const short8*)(&E[(wave*32 + r)*72 + c*8]);
      *(short8*)(hb + (size_t)ge*64 + c*8) = v;
    }
  }
}

// ---- fused GEMM2 + tensor product, 32x32x16 MFMA. 256 thr = 4 waves x 32 edges.
// 50 j-tiles of 32; u is reg-quad-uniform in every region; lane-halves cover
// disjoint wi -> no cross-lane reduce. G pre-packed; LDS double-buffer 2-tile
// chunks (8KB) via global_load_lds; blockIdx%25 stagger (j-sum commutes).
__global__ __launch_bounds__(256, 4) void k_tp(
    const unsigned short* __restrict__ hb,
    const unsigned short* __restrict__ G,
    const float* __restrict__ fc2b,
    const int* __restrict__ eidx,
    const float* __restrict__ node_attr,
    const float* __restrict__ edge_sh,
    int* __restrict__ cursor,
    float* __restrict__ tp) {
  __shared__ short Gs[2][4096];               // 16,384 B (2 tiles/chunk)
  __shared__ unsigned short wls[4][2048];     // 16,384 B bf16 coef tables
  __shared__ float b2s[JTOT];                 //  6,400 B
  __shared__ int pos_s[4][32];                //    512 B   (total 39,680 B)
  const int tid = threadIdx.x;
  const int wave = tid >> 6, lane = tid & 63;
  for (int i = tid; i < JTOT; i += 256) b2s[i] = fc2b[i];

  const int e0w = blockIdx.x * 128 + wave * 32;
  unsigned short* Wt = &wls[wave][0];
  {
    int el = lane & 31, hh = lane >> 5;
    int e = e0w + el;
    bool valid = e < NEDGES;
    int dst = valid ? eidx[NEDGES + e] : 0;
    const float* na = node_attr + (size_t)dst * DNODE;
    if (hh == 0) {
      pos_s[wave][el] = valid ? atomicAdd(&cursor[eidx[e]], 1) : 0;
      #pragma unroll
      for (int u = 0; u < 32; u += 4) {
        float4 v = valid ? *(const float4*)(na + u) : make_float4(0.f,0.f,0.f,0.f);
        Wt[(u+0)*32 + el] = f2bf(v.x);
        Wt[(u+1)*32 + el] = f2bf(v.y);
        Wt[(u+2)*32 + el] = f2bf(v.z);
        Wt[(u+3)*32 + el] = f2bf(v.w);
      }
    } else {
      float4 sh = valid ? *(const float4*)(edge_sh + 4*(size_t)e) : make_float4(0.f,0.f,0.f,0.f);
      const float rs3 = 0.57735026918962576f;
      #pragma unroll
      for (int u = 0; u < 8; u++) {
        float v0 = valid ? na[32 + u*3 + 0] : 0.f;
        float v1 = valid ? na[32 + u*3 + 1] : 0.f;
        float v2 = valid ? na[32 + u*3 + 2] : 0.f;
        Wt[(32 + u*3 + 0)*32 + el] = f2bf(v0);
        Wt[(32 + u*3 + 1)*32 + el] = f2bf(v1);
        Wt[(32 + u*3 + 2)*32 + el] = f2bf(v2);
        Wt[(56 + u)*32 + el] = f2bf((v0*sh.y + v1*sh.z + v2*sh.w) * rs3);
      }
    }
  }

  const int col = lane & 31, h = lane >> 5;
  const int e = e0w + col;
  const bool vld = e < NEDGES;
  float sh0c, sh1c[3];
  short8 bfr[4];
  const short8 zfrag = {0,0,0,0,0,0,0,0};
  if (vld) {
    float4 sh = *(const float4*)(edge_sh + 4*(size_t)e);
    sh0c = sh.x; sh1c[0] = sh.y; sh1c[1] = sh.z; sh1c[2] = sh.w;
    const unsigned short* hp = hb + (size_t)e * 64;
    #pragma unroll
    for (int s = 0; s < 4; s++)
      bfr[s] = *(const short8*)(hp + s*16 + h*8);
  } else {
    sh0c = 0.f; sh1c[0] = sh1c[1] = sh1c[2] = 0.f;
    #pragma unroll
    for (int s = 0; s < 4; s++) bfr[s] = zfrag;
  }

  float sacc[16], vacc[12];
  #pragma unroll
  for (int i = 0; i < 16; i++) sacc[i] = 0.f;
  #pragma unroll
  for (int i = 0; i < 12; i++) vacc[i] = 0.f;

  // stage chunk ch (2 tiles = 4096 shorts = 512 granules) into Gs[b]
  auto stage = [&](int ch, int b) {
    const unsigned short* gsrc = G + (size_t)ch * 4096 + tid * 8;
    #pragma unroll
    for (int i = 0; i < 2; i++)
      async_ld16(&Gs[b][(i*256 + wave*64) * 8], gsrc + i*256*8);
  };

  int buf = 0;
  auto gemm_tile = [&](int jt, int t) -> floatx16 {
    const short* gb = &Gs[buf][t * 2048];
    short8 a0 = *(const short8*)(gb + lane*8);
    short8 a1 = *(const short8*)(gb + 512 + lane*8);
    short8 a2 = *(const short8*)(gb + 1024 + lane*8);
    short8 a3 = *(const short8*)(gb + 1536 + lane*8);
    floatx16 C;
    #pragma unroll
    for (int q = 0; q < 4; q++) {
      float4 b = *(const float4*)&b2s[jt*32 + 8*q + 4*h];
      C[q*4+0] = b.x; C[q*4+1] = b.y; C[q*4+2] = b.z; C[q*4+3] = b.w;
    }
    C = __builtin_amdgcn_mfma_f32_32x32x16_bf16(a0, bfr[0], C, 0, 0, 0);
    C = __builtin_amdgcn_mfma_f32_32x32x16_bf16(a1, bfr[1], C, 0, 0, 0);
    C = __builtin_amdgcn_mfma_f32_32x32x16_bf16(a2, bfr[2], C, 0, 0, 0);
    C = __builtin_amdgcn_mfma_f32_32x32x16_bf16(a3, bfr[3], C, 0, 0, 0);
    return C;
  };
  auto apply_s = [&](const floatx16& C, float cf) {        // w1/w4
    #pragma unroll
    for (int i = 0; i < 16; i++) sacc[i] = fmaf(cf, C[i], sacc[i]);
  };
  auto apply_w2 = [&](const floatx16& C, int ubase) {
    #pragma unroll
    for (int q = 0; q < 4; q++) {
      const int u = ubase + q;
      #pragma unroll
      for (int c = 0; c < 3; c++) {
        float cf = bf2f(Wt[(32 + u*3 + c)*32 + col]) * sh0c;
        #pragma unroll
        for (int r = 0; r < 4; r++)
          vacc[c*4+r] = fmaf(cf, C[q*4+r], vacc[c*4+r]);
      }
    }
  };
  auto apply_w3 = [&](const floatx16& C, int ubase) {
    #pragma unroll
    for (int q = 0; q < 4; q++) {
      float sv = bf2f(Wt[(ubase + q)*32 + col]);
      #pragma unroll
      for (int c = 0; c < 3; c++) {
        float cf = sv * sh1c[c];
        #pragma unroll
        for (int r = 0; r < 4; r++)
          vacc[c*4+r] = fmaf(cf, C[q*4+r], vacc[c*4+r]);
      }
    }
  };

  const int cc0 = blockIdx.x % 25;
  stage(cc0, 0);
  __syncthreads();

  #pragma unroll 1
  for (int cc = 0; cc < 25; cc++) {
    int c = cc0 + cc; if (c >= 25) c -= 25;
    if (cc < 24) { int cn = c + 1; if (cn >= 25) cn = 0; stage(cn, buf ^ 1); }
    const int jt0 = c * 2;
    if (jt0 < 32) {                    // w1: u = jt
      floatx16 C0 = gemm_tile(jt0, 0);
      apply_s(C0, bf2f(Wt[jt0*32 + col]) * sh0c);
      floatx16 C1 = gemm_tile(jt0 + 1, 1);
      apply_s(C1, bf2f(Wt[(jt0+1)*32 + col]) * sh0c);
    } else if (jt0 == 32) {            // w2: u = (jt-32)*4 + q
      floatx16 C0 = gemm_tile(32, 0);
      apply_w2(C0, 0);
      floatx16 C1 = gemm_tile(33, 1);
      apply_w2(C1, 4);
    } else if (jt0 < 42) {             // w3: u = (jt-34)*4 + q
      floatx16 C0 = gemm_tile(jt0, 0);
      apply_w3(C0, (jt0 - 34) * 4);
      floatx16 C1 = gemm_tile(jt0 + 1, 1);
      apply_w3(C1, (jt0 - 33) * 4);
    } else {                           // w4: u = jt-42, coef = dot[u]
      floatx16 C0 = gemm_tile(jt0, 0);
      apply_s(C0, bf2f(Wt[(56 + jt0 - 42)*32 + col]));
      floatx16 C1 = gemm_tile(jt0 + 1, 1);
      apply_s(C1, bf2f(Wt[(56 + jt0 - 41)*32 + col]));
    }
    buf ^= 1;
    __syncthreads();
  }

  // ---- epilogue: direct stores (both lane-halves own disjoint wi)
  const float ascale = 0.15811388300841897f;   // 1/sqrt(40)
  if (vld) {
    float* rowp = tp + (size_t)pos_s[wave][col] * DNODE;
    #pragma unroll
    for (int q = 0; q < 4; q++) {      // out_s wi = 8q+4h+r
      float4 v = make_float4(ascale*sacc[q*4+0], ascale*sacc[q*4+1],
                             ascale*sacc[q*4+2], ascale*sacc[q*4+3]);
      *(float4*)(rowp + 8*q + 4*h) = v;
    }
    float tmp[12];                     // out_v wi = r+4h: rowp[32+(r+4h)*3+c]
    #pragma unroll
    for (int r = 0; r < 4; r++)
      #pragma unroll
      for (int c = 0; c < 3; c++) tmp[r*3 + c] = ascale * vacc[c*4 + r];
    #pragma unroll
    for (int j = 0; j < 3; j++)
      *(float4*)(rowp + 32 + 12*h + j*4) = *(float4*)&tmp[j*4];
  }
}

// ---- per-node mean + residual + BN partials; last block reduces pstat -> stats
__global__ __launch_bounds__(256) void k_gather(const float* __restrict__ tp,
                                                const int* __restrict__ offs,
                                                const float* __restrict__ node_attr,
                                                float* __restrict__ pre,
                                                float* __restrict__ pstat,
                                                int* __restrict__ gdone,
                                                float* __restrict__ stats) {
  __shared__ float redS[4*64], redQ[4*64];
  __shared__ int amLast;
  int t = threadIdx.x, wave = t >> 6, lane = t & 63;
  int gw = blockIdx.x * 4 + wave;
  const int W = 640 * 4;
  int off = (lane < DNODE) ? lane : 0;
  float ssum = 0.f, ssq = 0.f;
  for (int n = gw; n < NNODES; n += W) {
    int beg = offs[n], end = offs[n+1];
    float acc = 0.f;
    int i = beg;
    for (; i + 4 <= end; i += 4) {
      float v0 = tp[(size_t)(i+0)*DNODE + off];
      float v1 = tp[(size_t)(i+1)*DNODE + off];
      float v2 = tp[(size_t)(i+2)*DNODE + off];
      float v3 = tp[(size_t)(i+3)*DNODE + off];
      acc += (v0 + v1) + (v2 + v3);
    }
    for (; i < end; i++) acc += tp[(size_t)i*DNODE + off];
    int c = end - beg; if (c < 1) c = 1;
    float m = acc / (float)c + node_attr[(size_t)n*DNODE + off];
    if (lane < DNODE) { pre[(size_t)n*DNODE + lane] = m; ssum += m; ssq += m*m; }
  }
  redS[wave*64 + lane] = ssum;
  redQ[wave*64 + lane] = ssq;
  __syncthreads();
  if (wave == 0 && lane < DNODE) {
    float a = redS[lane] + redS[64+lane] + redS[128+lane] + redS[192+lane];
    float b = redQ[lane] + redQ[64+lane] + redQ[128+lane] + redQ[192+lane];
    pstat[(size_t)blockIdx.x*112 + lane] = a;
    pstat[(size_t)blockIdx.x*112 + 56 + lane] = b;
  }
  __syncthreads();
  if (t == 0) {
    __threadfence();
    amLast = (atomicAdd(gdone, 1) == 639) ? 1 : 0;
  }
  __syncthreads();
  if (amLast) {
    __threadfence();
    int f = t & 127, hh = t >> 7;
    float v = 0.f;
    if (f < 112) {
      #pragma unroll 8
      for (int b = hh; b < 640; b += 2) v += pstat[(size_t)b*112 + f];
      redS[hh*128 + f] = v;
    }
    __syncthreads();
    if (t < 112) stats[t] = redS[t] + redS[128 + t];
  }
}

__global__ __launch_bounds__(256) void k_norm(const float* __restrict__ pre,
                                              const float* __restrict__ stats,
                                              const float* __restrict__ gs,
                                              const float* __restrict__ bs,
                                              const float* __restrict__ gv,
                                              float* __restrict__ out) {
  int idx = blockIdx.x * 256 + threadIdx.x;
  if (idx >= NNODES * DNODE) return;
  int n = idx / DNODE;
  int d = idx - n * DNODE;
  float val = pre[idx];
  const float invN = 1.f / (float)NNODES;
  float res;
  if (d < 32) {
    float mu = stats[d] * invN;
    float var = stats[56 + d] * invN - mu * mu;
    res = (val - mu) * rsqrtf(var + 1e-4f) * gs[d] + bs[d];
  } else {
    int wi = (d - 32) / 3;
    float vn = (stats[56 + 32 + wi*3] + stats[56 + 32 + wi*3 + 1] +
                stats[56 + 32 + wi*3 + 2]) * (invN / 3.f);
    res = val * rsqrtf(vn + 1e-4f) * gv[wi];
  }
  out[idx] = res;
}

extern "C" void kernel_launch(void* const* d_in, const int* in_sizes, int n_in,
                              void* d_out, int out_size, void* d_ws, size_t ws_size,
                              hipStream_t stream) {
  const float* node_attr = (const float*)d_in[0];
  const int*   eidx      = (const int*)d_in[1];
  const float* edge_attr = (const float*)d_in[2];
  const float* edge_sh   = (const float*)d_in[3];
  const float* fc1w      = (const float*)d_in[4];
  const float* fc1b      = (const float*)d_in[5];
  const float* fc2w      = (const float*)d_in[6];
  const float* fc2b      = (const float*)d_in[7];
  const float* gs        = (const float*)d_in[8];
  const float* bs        = (const float*)d_in[9];
  const float* gv        = (const float*)d_in[10];

  float* ws = (float*)d_ws;
  float* tp    = ws;                                    // 5,600,000
  float* pre   = ws + 5600000;                          // 560,000
  float* stats = ws + 6160000;                          // 112 (pad 128)
  float* pstat = ws + 6160128;                          // 640*112 = 71,680
  int*   offs  = (int*)(ws + 6231808);                  // 10,001 (pad 10,008)
  int*   cursor= (int*)(ws + 6241816);                  // 10,000
  int*   gdone = (int*)(ws + 6251816);                  // 1 (pad 8)
  unsigned short* G  = (unsigned short*)(ws + 6251824); // 102,400 shorts (16B-aligned)
  unsigned short* hb = (unsigned short*)(ws + 6303024); // 6,400,000 shorts
  // end = 9,503,024 floats ≈ 38.0 MB

  k_hidtr<<<EBLK + TBLK + 1, 256, 0, stream>>>(edge_attr, fc1w, fc1b, fc2w, eidx,
                                               offs, cursor, gdone, hb, G);
  k_tp<<<782, 256, 0, stream>>>(hb, G, fc2b, eidx, node_attr, edge_sh, cursor, tp);
  k_gather<<<640, 256, 0, stream>>>(tp, offs, node_attr, pre, pstat, gdone, stats);
  k_norm<<<(NNODES * DNODE + 255) / 256, 256, 0, stream>>>(pre, stats, gs, bs, gv, (float*)d_out);
}

// Round 10
// 225.985 us; speedup vs baseline: 1.3810x; 1.3810x over previous
//
#include <hip/hip_runtime.h>
#include <stdint.h>

#define NNODES 10000
#define NEDGES 100000
#define DNODE 56
#define JTOT 1600
#define EBLK 782    // hidden-GEMM blocks (128 edges each)
#define TBLK 400    // G pre-pack blocks

typedef __attribute__((ext_vector_type(8))) short short8;
typedef __attribute__((ext_vector_type(4))) float floatx4;
typedef __attribute__((ext_vector_type(16))) float floatx16;

__device__ __forceinline__ unsigned short f2bf(float f) {
  unsigned u = __float_as_uint(f);
  u = u + 0x7fffu + ((u >> 16) & 1u);
  return (unsigned short)(u >> 16);
}
__device__ __forceinline__ float bf2f(unsigned short u) {
  return __uint_as_float(((unsigned)u) << 16);
}

__device__ __forceinline__ float mishf(float x) {
  float e = __expf(x);
  float z = 1.f + e; z = z * z;
  float t = (z - 1.f) / (z + 1.f);
  t = (x > 40.f) ? 1.f : t;
  return x * t;
}

// async 16B global -> LDS; lds base wave-uniform (HW adds lane*16)
__device__ __forceinline__ void async_ld16(void* lds, const void* gp) {
  __builtin_amdgcn_global_load_lds(
      (const __attribute__((address_space(1))) unsigned int*)gp,
      (__attribute__((address_space(3))) unsigned int*)lds, 16, 0, 0);
}

// ---- fused: [0,EBLK) hidden GEMM + distributed global histogram;
//             [EBLK,EBLK+TBLK) G pre-pack for 32x32x16 A-fragments.
__global__ __launch_bounds__(256, 4) void k_hidtr(const float* __restrict__ ea,
                                                  const float* __restrict__ fc1w,
                                                  const float* __restrict__ fc1b,
                                                  const float* __restrict__ fc2w,
                                                  const int* __restrict__ eidx,
                                                  int* __restrict__ cntn,
                                                  unsigned short* __restrict__ hb,
                                                  unsigned short* __restrict__ G) {
  const int bid = blockIdx.x, tid = threadIdx.x;

  if (bid >= EBLK) {           // ---- G pre-pack for 32x32x16 A-fragments
    int idx = (bid - EBLK) * 256 + tid;
    if (idx < 64 * JTOT) {
      int jt = idx >> 11;             // 2048 shorts per tile
      int r  = idx & 2047;
      int s  = r >> 9;                // sub-K (0..3)
      int l  = (r >> 3) & 63;         // lane
      int i  = r & 7;
      int j  = jt * 32 + (l & 31);
      int k  = s * 16 + (l >> 5) * 8 + i;
      G[idx] = f2bf(fc2w[k * JTOT + j]);
    }
    return;
  }

  // ---- hidden GEMM: 128 edges/block, 4 waves x 32 edges, MFMA 16x16x32 bf16
  __shared__ unsigned short T[64 * 72];    // fc1^T bf16 (9,216 B)
  __shared__ unsigned short E[128 * 72];   // ea bf16 -> h staging (18,432 B)
  __shared__ float b1s[64];
  const int e0 = bid * 128;
  if (tid < 128) {
    int e = e0 + tid;
    if (e < NEDGES) atomicAdd(&cntn[eidx[e]], 1);
  }
  if (tid < 64) b1s[tid] = fc1b[tid];
  #pragma unroll
  for (int it = 0; it < 4; it++) {
    int q = tid + 256 * it;
    int k = q >> 4, j4 = (q & 15) * 4;
    float4 v = *(const float4*)(fc1w + (size_t)q * 4);
    T[(j4+0)*72 + k] = f2bf(v.x);
    T[(j4+1)*72 + k] = f2bf(v.y);
    T[(j4+2)*72 + k] = f2bf(v.z);
    T[(j4+3)*72 + k] = f2bf(v.w);
  }
  #pragma unroll
  for (int it = 0; it < 8; it++) {
    int q = tid + 256 * it;
    int e = q >> 4, k4 = (q & 15) * 4;
    int ge = e0 + e;
    float4 v = (ge < NEDGES) ? *(const float4*)(ea + (size_t)ge * 64 + k4)
                             : make_float4(0.f, 0.f, 0.f, 0.f);
    ushort4 p;
    p.x = f2bf(v.x); p.y = f2bf(v.y); p.z = f2bf(v.z); p.w = f2bf(v.w);
    *(ushort4*)(&E[e*72 + k4]) = p;
  }
  __syncthreads();

  const int wave = tid >> 6, lane = tid & 63, col = lane & 15, rg = lane >> 4;
  short8 bf[2][2];
  #pragma unroll
  for (int nt = 0; nt < 2; nt++) {
    int er = wave*32 + nt*16 + col;
    bf[nt][0] = *(const short8*)(&E[er*72 + rg*8]);
    bf[nt][1] = *(const short8*)(&E[er*72 + 32 + rg*8]);
  }
  floatx4 acc[4][2];
  #pragma unroll
  for (int jt = 0; jt < 4; jt++) {
    int j = jt*16 + col;
    short8 a0 = *(const short8*)(&T[j*72 + rg*8]);
    short8 a1 = *(const short8*)(&T[j*72 + 32 + rg*8]);
    float4 bb = *(const float4*)(&b1s[jt*16 + rg*4]);
    #pragma unroll
    for (int nt = 0; nt < 2; nt++) {
      floatx4 c = {bb.x, bb.y, bb.z, bb.w};
      c = __builtin_amdgcn_mfma_f32_16x16x32_bf16(a0, bf[nt][0], c, 0, 0, 0);
      c = __builtin_amdgcn_mfma_f32_16x16x32_bf16(a1, bf[nt][1], c, 0, 0, 0);
      acc[jt][nt] = c;
    }
  }
  #pragma unroll
  for (int jt = 0; jt < 4; jt++)
    #pragma unroll
    for (int nt = 0; nt < 2; nt++) {
      ushort4 p;
      p.x = f2bf(mishf(acc[jt][nt][0]));
      p.y = f2bf(mishf(acc[jt][nt][1]));
      p.z = f2bf(mishf(acc[jt][nt][2]));
      p.w = f2bf(mishf(acc[jt][nt][3]));
      *(ushort4*)(&E[(wave*32 + nt*16 + col)*72 + jt*16 + rg*4]) = p;
    }
  #pragma unroll
  for (int it = 0; it < 4; it++) {
    int g = it*64 + lane;
    int r = g >> 3, c = g & 7;
    int ge = e0 + wave*32 + r;
    if (ge < NEDGES) {
      short8 v = *(const short8*)(&E[(wave*32 + r)*72 + c*8]);
      *(short8*)(hb + (size_t)ge*64 + c*8) = v;
    }
  }
}

// ---- scan: offs/cursor from cntn (single block, R4/R8-proven); zeroes gdone
__global__ __launch_bounds__(1024) void k_scan(const int* __restrict__ cntn,
                                               int* __restrict__ offs,
                                               int* __restrict__ cursor,
                                               int* __restrict__ gdone) {
  __shared__ int ts[1024];
  int t = threadIdx.x;
  if (t == 0) gdone[0] = 0;
  int base = t * 10;
  int loc[10]; int s = 0;
  #pragma unroll
  for (int i = 0; i < 10; i++) {
    int idx = base + i;
    int v = (idx < NNODES) ? cntn[idx] : 0;
    loc[i] = s; s += v;
  }
  ts[t] = s;
  __syncthreads();
  for (int off = 1; off < 1024; off <<= 1) {
    int v = (t >= off) ? ts[t - off] : 0;
    __syncthreads();
    ts[t] += v;
    __syncthreads();
  }
  int excl = (t == 0) ? 0 : ts[t - 1];
  #pragma unroll
  for (int i = 0; i < 10; i++) {
    int idx = base + i;
    if (idx < NNODES) { int o = excl + loc[i]; offs[idx] = o; cursor[idx] = o; }
  }
  if (t == 1023) offs[NNODES] = ts[1023];
}

// ---- fused GEMM2 + tensor product, 32x32x16 MFMA. 256 thr = 4 waves x 32 edges.
// 50 j-tiles of 32; u reg-quad-uniform in all regions; lane-halves own disjoint wi.
// G pre-packed; LDS double-buffer 2-tile chunks via global_load_lds; %25 stagger.
__global__ __launch_bounds__(256, 4) void k_tp(
    const unsigned short* __restrict__ hb,
    const unsigned short* __restrict__ G,
    const float* __restrict__ fc2b,
    const int* __restrict__ eidx,
    const float* __restrict__ node_attr,
    const float* __restrict__ edge_sh,
    int* __restrict__ cursor,
    float* __restrict__ tp) {
  __shared__ short Gs[2][4096];               // 16,384 B (2 tiles/chunk)
  __shared__ unsigned short wls[4][2048];     // 16,384 B bf16 coef tables
  __shared__ float b2s[JTOT];                 //  6,400 B
  __shared__ int pos_s[4][32];                //    512 B   (total 39,680 B)
  const int tid = threadIdx.x;
  const int wave = tid >> 6, lane = tid & 63;
  for (int i = tid; i < JTOT; i += 256) b2s[i] = fc2b[i];

  const int e0w = blockIdx.x * 128 + wave * 32;
  unsigned short* Wt = &wls[wave][0];
  {
    int el = lane & 31, hh = lane >> 5;
    int e = e0w + el;
    bool valid = e < NEDGES;
    int dst = valid ? eidx[NEDGES + e] : 0;
    const float* na = node_attr + (size_t)dst * DNODE;
    if (hh == 0) {
      pos_s[wave][el] = valid ? atomicAdd(&cursor[eidx[e]], 1) : 0;
      #pragma unroll
      for (int u = 0; u < 32; u += 4) {
        float4 v = valid ? *(const float4*)(na + u) : make_float4(0.f,0.f,0.f,0.f);
        Wt[(u+0)*32 + el] = f2bf(v.x);
        Wt[(u+1)*32 + el] = f2bf(v.y);
        Wt[(u+2)*32 + el] = f2bf(v.z);
        Wt[(u+3)*32 + el] = f2bf(v.w);
      }
    } else {
      float4 sh = valid ? *(const float4*)(edge_sh + 4*(size_t)e) : make_float4(0.f,0.f,0.f,0.f);
      const float rs3 = 0.57735026918962576f;
      #pragma unroll
      for (int u = 0; u < 8; u++) {
        float v0 = valid ? na[32 + u*3 + 0] : 0.f;
        float v1 = valid ? na[32 + u*3 + 1] : 0.f;
        float v2 = valid ? na[32 + u*3 + 2] : 0.f;
        Wt[(32 + u*3 + 0)*32 + el] = f2bf(v0);
        Wt[(32 + u*3 + 1)*32 + el] = f2bf(v1);
        Wt[(32 + u*3 + 2)*32 + el] = f2bf(v2);
        Wt[(56 + u)*32 + el] = f2bf((v0*sh.y + v1*sh.z + v2*sh.w) * rs3);
      }
    }
  }

  const int col = lane & 31, h = lane >> 5;
  const int e = e0w + col;
  const bool vld = e < NEDGES;
  float sh0c, sh1c[3];
  short8 bfr[4];
  const short8 zfrag = {0,0,0,0,0,0,0,0};
  if (vld) {
    float4 sh = *(const float4*)(edge_sh + 4*(size_t)e);
    sh0c = sh.x; sh1c[0] = sh.y; sh1c[1] = sh.z; sh1c[2] = sh.w;
    const unsigned short* hp = hb + (size_t)e * 64;
    #pragma unroll
    for (int s = 0; s < 4; s++)
      bfr[s] = *(const short8*)(hp + s*16 + h*8);
  } else {
    sh0c = 0.f; sh1c[0] = sh1c[1] = sh1c[2] = 0.f;
    #pragma unroll
    for (int s = 0; s < 4; s++) bfr[s] = zfrag;
  }

  float sacc[16], vacc[12];
  #pragma unroll
  for (int i = 0; i < 16; i++) sacc[i] = 0.f;
  #pragma unroll
  for (int i = 0; i < 12; i++) vacc[i] = 0.f;

  auto stage = [&](int ch, int b) {
    const unsigned short* gsrc = G + (size_t)ch * 4096 + tid * 8;
    #pragma unroll
    for (int i = 0; i < 2; i++)
      async_ld16(&Gs[b][(i*256 + wave*64) * 8], gsrc + i*256*8);
  };

  int buf = 0;
  auto gemm_tile = [&](int jt, int t) -> floatx16 {
    const short* gb = &Gs[buf][t * 2048];
    short8 a0 = *(const short8*)(gb + lane*8);
    short8 a1 = *(const short8*)(gb + 512 + lane*8);
    short8 a2 = *(const short8*)(gb + 1024 + lane*8);
    short8 a3 = *(const short8*)(gb + 1536 + lane*8);
    floatx16 C;
    #pragma unroll
    for (int q = 0; q < 4; q++) {
      float4 b = *(const float4*)&b2s[jt*32 + 8*q + 4*h];
      C[q*4+0] = b.x; C[q*4+1] = b.y; C[q*4+2] = b.z; C[q*4+3] = b.w;
    }
    C = __builtin_amdgcn_mfma_f32_32x32x16_bf16(a0, bfr[0], C, 0, 0, 0);
    C = __builtin_amdgcn_mfma_f32_32x32x16_bf16(a1, bfr[1], C, 0, 0, 0);
    C = __builtin_amdgcn_mfma_f32_32x32x16_bf16(a2, bfr[2], C, 0, 0, 0);
    C = __builtin_amdgcn_mfma_f32_32x32x16_bf16(a3, bfr[3], C, 0, 0, 0);
    return C;
  };
  auto apply_s = [&](const floatx16& C, float cf) {        // w1/w4
    #pragma unroll
    for (int i = 0; i < 16; i++) sacc[i] = fmaf(cf, C[i], sacc[i]);
  };
  auto apply_w2 = [&](const floatx16& C, int ubase) {
    #pragma unroll
    for (int q = 0; q < 4; q++) {
      const int u = ubase + q;
      #pragma unroll
      for (int c = 0; c < 3; c++) {
        float cf = bf2f(Wt[(32 + u*3 + c)*32 + col]) * sh0c;
        #pragma unroll
        for (int r = 0; r < 4; r++)
          vacc[c*4+r] = fmaf(cf, C[q*4+r], vacc[c*4+r]);
      }
    }
  };
  auto apply_w3 = [&](const floatx16& C, int ubase) {
    #pragma unroll
    for (int q = 0; q < 4; q++) {
      float sv = bf2f(Wt[(ubase + q)*32 + col]);
      #pragma unroll
      for (int c = 0; c < 3; c++) {
        float cf = sv * sh1c[c];
        #pragma unroll
        for (int r = 0; r < 4; r++)
          vacc[c*4+r] = fmaf(cf, C[q*4+r], vacc[c*4+r]);
      }
    }
  };

  const int cc0 = blockIdx.x % 25;
  stage(cc0, 0);
  __syncthreads();

  #pragma unroll 1
  for (int cc = 0; cc < 25; cc++) {
    int c = cc0 + cc; if (c >= 25) c -= 25;
    if (cc < 24) { int cn = c + 1; if (cn >= 25) cn = 0; stage(cn, buf ^ 1); }
    const int jt0 = c * 2;
    if (jt0 < 32) {                    // w1: u = jt
      floatx16 C0 = gemm_tile(jt0, 0);
      apply_s(C0, bf2f(Wt[jt0*32 + col]) * sh0c);
      floatx16 C1 = gemm_tile(jt0 + 1, 1);
      apply_s(C1, bf2f(Wt[(jt0+1)*32 + col]) * sh0c);
    } else if (jt0 == 32) {            // w2: u = (jt-32)*4 + q
      floatx16 C0 = gemm_tile(32, 0);
      apply_w2(C0, 0);
      floatx16 C1 = gemm_tile(33, 1);
      apply_w2(C1, 4);
    } else if (jt0 < 42) {             // w3: u = (jt-34)*4 + q
      floatx16 C0 = gemm_tile(jt0, 0);
      apply_w3(C0, (jt0 - 34) * 4);
      floatx16 C1 = gemm_tile(jt0 + 1, 1);
      apply_w3(C1, (jt0 - 33) * 4);
    } else {                           // w4: u = jt-42, coef = dot[u]
      floatx16 C0 = gemm_tile(jt0, 0);
      apply_s(C0, bf2f(Wt[(56 + jt0 - 42)*32 + col]));
      floatx16 C1 = gemm_tile(jt0 + 1, 1);
      apply_s(C1, bf2f(Wt[(56 + jt0 - 41)*32 + col]));
    }
    buf ^= 1;
    __syncthreads();
  }

  // ---- epilogue: direct stores (lane-halves own disjoint wi)
  const float ascale = 0.15811388300841897f;   // 1/sqrt(40)
  if (vld) {
    float* rowp = tp + (size_t)pos_s[wave][col] * DNODE;
    #pragma unroll
    for (int q = 0; q < 4; q++) {      // out_s wi = 8q+4h+r
      float4 v = make_float4(ascale*sacc[q*4+0], ascale*sacc[q*4+1],
                             ascale*sacc[q*4+2], ascale*sacc[q*4+3]);
      *(float4*)(rowp + 8*q + 4*h) = v;
    }
    float tmp[12];                     // out_v wi = r+4h: rowp[32+(r+4h)*3+c]
    #pragma unroll
    for (int r = 0; r < 4; r++)
      #pragma unroll
      for (int c = 0; c < 3; c++) tmp[r*3 + c] = ascale * vacc[c*4 + r];
    #pragma unroll
    for (int j = 0; j < 3; j++)
      *(float4*)(rowp + 32 + 12*h + j*4) = *(float4*)&tmp[j*4];
  }
}

// ---- per-node mean + residual + BN partials; last block reduces pstat -> stats
__global__ __launch_bounds__(256) void k_gather(const float* __restrict__ tp,
                                                const int* __restrict__ offs,
                                                const float* __restrict__ node_attr,
                                                float* __restrict__ pre,
                                                float* __restrict__ pstat,
                                                int* __restrict__ gdone,
                                                float* __restrict__ stats) {
  __shared__ float redS[4*64], redQ[4*64];
  __shared__ int amLast;
  int t = threadIdx.x, wave = t >> 6, lane = t & 63;
  int gw = blockIdx.x * 4 + wave;
  const int W = 640 * 4;
  int off = (lane < DNODE) ? lane : 0;
  float ssum = 0.f, ssq = 0.f;
  for (int n = gw; n < NNODES; n += W) {
    int beg = offs[n], end = offs[n+1];
    float acc = 0.f;
    int i = beg;
    for (; i + 4 <= end; i += 4) {
      float v0 = tp[(size_t)(i+0)*DNODE + off];
      float v1 = tp[(size_t)(i+1)*DNODE + off];
      float v2 = tp[(size_t)(i+2)*DNODE + off];
      float v3 = tp[(size_t)(i+3)*DNODE + off];
      acc += (v0 + v1) + (v2 + v3);
    }
    for (; i < end; i++) acc += tp[(size_t)i*DNODE + off];
    int c = end - beg; if (c < 1) c = 1;
    float m = acc / (float)c + node_attr[(size_t)n*DNODE + off];
    if (lane < DNODE) { pre[(size_t)n*DNODE + lane] = m; ssum += m; ssq += m*m; }
  }
  redS[wave*64 + lane] = ssum;
  redQ[wave*64 + lane] = ssq;
  __syncthreads();
  if (wave == 0 && lane < DNODE) {
    float a = redS[lane] + redS[64+lane] + redS[128+lane] + redS[192+lane];
    float b = redQ[lane] + redQ[64+lane] + redQ[128+lane] + redQ[192+lane];
    pstat[(size_t)blockIdx.x*112 + lane] = a;
    pstat[(size_t)blockIdx.x*112 + 56 + lane] = b;
  }
  __syncthreads();
  if (t == 0) {
    __threadfence();
    amLast = (atomicAdd(gdone, 1) == 639) ? 1 : 0;
  }
  __syncthreads();
  if (amLast) {
    __threadfence();
    int f = t & 127, hh = t >> 7;
    float v = 0.f;
    if (f < 112) {
      #pragma unroll 8
      for (int b = hh; b < 640; b += 2) v += pstat[(size_t)b*112 + f];
      redS[hh*128 + f] = v;
    }
    __syncthreads();
    if (t < 112) stats[t] = redS[t] + redS[128 + t];
  }
}

__global__ __launch_bounds__(256) void k_norm(const float* __restrict__ pre,
                                              const float* __restrict__ stats,
                                              const float* __restrict__ gs,
                                              const float* __restrict__ bs,
                                              const float* __restrict__ gv,
                                              float* __restrict__ out) {
  int idx = blockIdx.x * 256 + threadIdx.x;
  if (idx >= NNODES * DNODE) return;
  int n = idx / DNODE;
  int d = idx - n * DNODE;
  float val = pre[idx];
  const float invN = 1.f / (float)NNODES;
  float res;
  if (d < 32) {
    float mu = stats[d] * invN;
    float var = stats[56 + d] * invN - mu * mu;
    res = (val - mu) * rsqrtf(var + 1e-4f) * gs[d] + bs[d];
  } else {
    int wi = (d - 32) / 3;
    float vn = (stats[56 + 32 + wi*3] + stats[56 + 32 + wi*3 + 1] +
                stats[56 + 32 + wi*3 + 2]) * (invN / 3.f);
    res = val * rsqrtf(vn + 1e-4f) * gv[wi];
  }
  out[idx] = res;
}

extern "C" void kernel_launch(void* const* d_in, const int* in_sizes, int n_in,
                              void* d_out, int out_size, void* d_ws, size_t ws_size,
                              hipStream_t stream) {
  const float* node_attr = (const float*)d_in[0];
  const int*   eidx      = (const int*)d_in[1];
  const float* edge_attr = (const float*)d_in[2];
  const float* edge_sh   = (const float*)d_in[3];
  const float* fc1w      = (const float*)d_in[4];
  const float* fc1b      = (const float*)d_in[5];
  const float* fc2w      = (const float*)d_in[6];
  const float* fc2b      = (const float*)d_in[7];
  const float* gs        = (const float*)d_in[8];
  const float* bs        = (const float*)d_in[9];
  const float* gv        = (const float*)d_in[10];

  float* ws = (float*)d_ws;
  float* tp    = ws;                                    // 5,600,000
  float* pre   = ws + 5600000;                          // 560,000
  float* stats = ws + 6160000;                          // 112 (pad 128)
  float* pstat = ws + 6160128;                          // 640*112 = 71,680
  int*   cntn  = (int*)(ws + 6231808);                  // 10,000
  int*   offs  = (int*)(ws + 6241808);                  // 10,001 (pad 10,008)
  int*   cursor= (int*)(ws + 6251816);                  // 10,000
  int*   gdone = (int*)(ws + 6261816);                  // 1 (pad 8)
  unsigned short* G  = (unsigned short*)(ws + 6261824); // 102,400 shorts (16B-aligned)
  unsigned short* hb = (unsigned short*)(ws + 6313024); // 6,400,000 shorts
  // end = 9,513,024 floats ≈ 38.1 MB

  hipMemsetAsync(cntn, 0, (size_t)10000 * 4, stream);
  k_hidtr<<<EBLK + TBLK, 256, 0, stream>>>(edge_attr, fc1w, fc1b, fc2w, eidx, cntn, hb, G);
  k_scan<<<1, 1024, 0, stream>>>(cntn, offs, cursor, gdone);
  k_tp<<<782, 256, 0, stream>>>(hb, G, fc2b, eidx, node_attr, edge_sh, cursor, tp);
  k_gather<<<640, 256, 0, stream>>>(tp, offs, node_attr, pre, pstat, gdone, stats);
  k_norm<<<(NNODES * DNODE + 255) / 256, 256, 0, stream>>>(pre, stats, gs, bs, gv, (float*)d_out);
}